// Round 10
// baseline (375.588 us; speedup 1.0000x reference)
//
#include <hip/hip_runtime.h>
#include <hip/hip_bf16.h>

// MHA forward: B=2, T=2048, D=1024, H=16 (head dim 64), causal. fp32 I/O (sniffed).
// R18: attn LDS-traffic cut, composition of two PROVEN pieces.
//      Diagnosis: kfrag/vfrag LDS addresses have no `wave` term -> all 8 waves
//      re-read identical K/V frags; frag traffic scales with (block q-rows)/
//      (wave q-rows). R9 (16 rows/wave) doubled traffic/row vs R0 (32/wave).
//      Now: R0's 32-rows-per-wave g-loop body x 8 waves = QBLK 256.
//      Per-CU LDS work -37% (71.8k -> 44.9k cyc) at the same 16 waves/CU.
//      Grid (8,16,2), pairing {qt,7-qt}, nkt=4qt+4. LDS 69.6KB (2 blocks/CU).
//      launch_bounds (512,4): VGPR cap 128 >= R0's ~100 working set.
//      out_gemm reverted to R13's 64x128 body (R17's 128^2 = 1 blk/CU, worse).
//      qkv/cvt = R13 verbatim.

typedef __attribute__((ext_vector_type(8))) short bf16x8;   // MFMA A/B frag
typedef __attribute__((ext_vector_type(4))) float f32x4;    // MFMA C/D frag
typedef __attribute__((ext_vector_type(4))) short s16x4;    // 4 bf16 = b64

#define QSCALE 0.18033688011f   // (1/sqrt(64)) * log2(e)

__device__ __forceinline__ int sniff_f32(const void* p) {
    const unsigned short* u = (const unsigned short*)p;
    int c = 0;
    for (int i = 0; i < 256; ++i) {
        int e = (u[i] >> 7) & 0xFF;
        c += (e >= 0x90) ? 1 : 0;
    }
    return c > 8;
}

__device__ __forceinline__ void async_copy16(const void* g, void* l) {
    __builtin_amdgcn_global_load_lds(
        (const __attribute__((address_space(1))) void*)g,
        (__attribute__((address_space(3))) void*)l, 16, 0, 0);
}

// ---------------------------------------------------------------------------
// Convert pass (unchanged)
// ---------------------------------------------------------------------------
struct Cvt { const void* src; __hip_bfloat16* dst; int n; };
struct CvtPack { Cvt a[9]; };

__global__ __launch_bounds__(256) void cvt_bf16(CvtPack pk) {
    const Cvt c = pk.a[blockIdx.y];
    const int f32 = sniff_f32(c.src);
    const int stride = gridDim.x * 256 * 8;
    for (int idx = (blockIdx.x * 256 + threadIdx.x) * 8; idx < c.n; idx += stride) {
        if (f32) {
            const float* s = (const float*)c.src + idx;
            f32x4 a0 = *(const f32x4*)s;
            f32x4 a1 = *(const f32x4*)(s + 4);
            union { __hip_bfloat16 h[8]; bf16x8 v; } u;
#pragma unroll
            for (int e = 0; e < 4; e++) u.h[e]     = (__hip_bfloat16)a0[e];
#pragma unroll
            for (int e = 0; e < 4; e++) u.h[4 + e] = (__hip_bfloat16)a1[e];
            *(bf16x8*)&c.dst[idx] = u.v;
        } else {
            *(bf16x8*)&c.dst[idx] = *(const bf16x8*)((const __hip_bfloat16*)c.src + idx);
        }
    }
}

// ---------------------------------------------------------------------------
// 128x128 GEMM-BT, 2-phase prefetch (R13). MODE: 0 = bf16 row-major out,
// 1 = fp32 row-major out, 2 = bf16 out into VT[b][h][d][t] via LDS-staged
// coalesced writes.
// ---------------------------------------------------------------------------
template <int MODE>
__device__ __forceinline__ void gemm_async_body(
    const __hip_bfloat16* __restrict__ A, const __hip_bfloat16* __restrict__ W,
    const __hip_bfloat16* __restrict__ bias, void* __restrict__ C,
    int M, int N, int K, int bm, int bn, float outscale,
    __hip_bfloat16* smem)
{
    const int tid  = threadIdx.x;
    const int wave = tid >> 6;
    const int lane = tid & 63;
    const int quad = lane >> 4;
    const int l15  = lane & 15;
    const int wr   = wave >> 1;
    const int wc   = wave & 1;

    const int srow = wave * 16 + (lane >> 2);
    const int scol = (lane & 3) * 8;
    const __hip_bfloat16* gA0 = A + (size_t)(bm + srow) * K + scol;
    const __hip_bfloat16* gB0 = W + (size_t)(bn + srow) * K + scol;

    f32x4 acc[4][4];
#pragma unroll
    for (int i = 0; i < 4; i++)
#pragma unroll
        for (int j = 0; j < 4; j++) acc[i][j] = (f32x4)0.0f;

#define QSTAGE(buf, k0) { \
        __hip_bfloat16* d_ = smem + (buf) * 8192 + wave * 512; \
        async_copy16(gA0 + (k0), d_); \
        async_copy16(gA0 + (size_t)64 * K + (k0), d_ + 2048); \
        async_copy16(gB0 + (k0), d_ + 4096); \
        async_copy16(gB0 + (size_t)64 * K + (k0), d_ + 4096 + 2048); \
    }

    const int nt = K >> 5;
    QSTAGE(0, 0);
    for (int t = 0; t < nt; ++t) {
        const int buf = t & 1;
        const __hip_bfloat16* sA = smem + buf * 8192;
        const __hip_bfloat16* sB = sA + 4096;
        if (t + 1 < nt) {
            QSTAGE(1 - buf, (t + 1) * 32);
            asm volatile("s_waitcnt vmcnt(4)" ::: "memory");
        } else {
            asm volatile("s_waitcnt vmcnt(0)" ::: "memory");
        }
        __builtin_amdgcn_s_barrier();

        bf16x8 af[4], bf[4];
#pragma unroll
        for (int i = 0; i < 4; i++)
            af[i] = *(const bf16x8*)&sA[(wr * 64 + i * 16 + l15) * 32 + quad * 8];
#pragma unroll
        for (int j = 0; j < 4; j++)
            bf[j] = *(const bf16x8*)&sB[(wc * 64 + j * 16 + l15) * 32 + quad * 8];
#pragma unroll
        for (int i = 0; i < 4; i++)
#pragma unroll
            for (int j = 0; j < 4; j++)
                acc[i][j] = __builtin_amdgcn_mfma_f32_16x16x32_bf16(af[i], bf[j], acc[i][j], 0, 0, 0);

        __builtin_amdgcn_s_barrier();
    }
#undef QSTAGE

    float bv[4];
#pragma unroll
    for (int j = 0; j < 4; j++)
        bv[j] = (float)bias[bn + wc * 64 + j * 16 + l15];

    if (MODE == 2) {
        __hip_bfloat16* sOut = smem;
        __syncthreads();
#pragma unroll
        for (int i = 0; i < 4; i++) {
            int tl = wr * 64 + i * 16 + quad * 4;
#pragma unroll
            for (int j = 0; j < 4; j++) {
                int dl = wc * 64 + j * 16 + l15;
                union { __hip_bfloat16 e[4]; s16x4 v; } u;
#pragma unroll
                for (int r = 0; r < 4; r++)
                    u.e[r] = (__hip_bfloat16)(acc[i][j][r] + bv[j]);
                *(s16x4*)&sOut[dl * 136 + tl] = u.v;
            }
        }
        __syncthreads();
        __hip_bfloat16* VTo = (__hip_bfloat16*)C;
        const int bb = bm >> 11, tt0 = bm & 2047;
#pragma unroll
        for (int g8 = 0; g8 < 8; g8++) {
            int idx = g8 * 256 + tid;
            int dl  = idx >> 4;
            int tc  = (idx & 15) * 8;
            int dg  = bn + dl;
            bf16x8 v = *(const bf16x8*)&sOut[dl * 136 + tc];
            *(bf16x8*)&VTo[(((size_t)bb * 16 + (dg >> 6)) * 64 + (dg & 63)) * 2048 + tt0 + tc] = v;
        }
    } else {
#pragma unroll
        for (int i = 0; i < 4; i++) {
#pragma unroll
            for (int j = 0; j < 4; j++) {
                int col = bn + wc * 64 + j * 16 + l15;
#pragma unroll
                for (int r = 0; r < 4; r++) {
                    int row = bm + wr * 64 + i * 16 + quad * 4 + r;
                    float v = (acc[i][j][r] + bv[j]) * outscale;
                    if (MODE == 1) ((float*)C)[(size_t)row * N + col] = v;
                    else ((__hip_bfloat16*)C)[(size_t)row * N + col] = (__hip_bfloat16)v;
                }
            }
        }
    }
}

__global__ __launch_bounds__(256, 2) void qkv_gemm(
    const __hip_bfloat16* __restrict__ x,
    const __hip_bfloat16* __restrict__ Wq, const __hip_bfloat16* __restrict__ bq, __hip_bfloat16* __restrict__ Q,
    const __hip_bfloat16* __restrict__ Wk, const __hip_bfloat16* __restrict__ bk, __hip_bfloat16* __restrict__ Kb,
    const __hip_bfloat16* __restrict__ Wv, const __hip_bfloat16* __restrict__ bv, __hip_bfloat16* __restrict__ VT,
    int M, int N, int K)
{
    __shared__ __hip_bfloat16 smem[128 * 136];
    if (blockIdx.z == 0)
        gemm_async_body<0>(x, Wq, bq, Q, M, N, K, blockIdx.x * 128, blockIdx.y * 128, QSCALE, smem);
    else if (blockIdx.z == 1)
        gemm_async_body<0>(x, Wk, bk, Kb, M, N, K, blockIdx.x * 128, blockIdx.y * 128, 1.0f, smem);
    else
        gemm_async_body<2>(x, Wv, bv, VT, M, N, K, blockIdx.x * 128, blockIdx.y * 128, 1.0f, smem);
}

// ---------------------------------------------------------------------------
// out_gemm 64x128, 2-phase prefetch (R13, reverted from R17's 128^2)
// ---------------------------------------------------------------------------
template <bool OF32>
__device__ __forceinline__ void gemm64_body(
    const __hip_bfloat16* __restrict__ A, const __hip_bfloat16* __restrict__ W,
    const __hip_bfloat16* __restrict__ bias, void* __restrict__ C,
    int M, int N, int K, int bm, int bn,
    __hip_bfloat16* smem)
{
    const int tid  = threadIdx.x;
    const int wave = tid >> 6;
    const int lane = tid & 63;
    const int quad = lane >> 4;
    const int l15  = lane & 15;

    const int srow = wave * 16 + (lane >> 2);
    const int scol = (lane & 3) * 8;
    const __hip_bfloat16* gA0 = A + (size_t)(bm + srow) * K + scol;
    const __hip_bfloat16* gB0 = W + (size_t)(bn + srow) * K + scol;

    f32x4 acc[4][2];
#pragma unroll
    for (int i = 0; i < 4; i++)
#pragma unroll
        for (int j = 0; j < 2; j++) acc[i][j] = (f32x4)0.0f;

#define OSTAGE(buf, k0) { \
        __hip_bfloat16* d_ = smem + (buf) * 6144; \
        async_copy16(gA0 + (k0), d_ + wave * 512); \
        async_copy16(gB0 + (k0), d_ + 2048 + wave * 512); \
        async_copy16(gB0 + (size_t)64 * K + (k0), d_ + 2048 + wave * 512 + 2048); \
    }

    const int nt = K >> 5;
    OSTAGE(0, 0);
    for (int t = 0; t < nt; ++t) {
        const int buf = t & 1;
        const __hip_bfloat16* sA = smem + buf * 6144;
        const __hip_bfloat16* sB = sA + 2048;
        if (t + 1 < nt) {
            OSTAGE(1 - buf, (t + 1) * 32);
            asm volatile("s_waitcnt vmcnt(3)" ::: "memory");
        } else {
            asm volatile("s_waitcnt vmcnt(0)" ::: "memory");
        }
        __builtin_amdgcn_s_barrier();

        bf16x8 af[4], bf[2];
#pragma unroll
        for (int i = 0; i < 4; i++)
            af[i] = *(const bf16x8*)&sA[(i * 16 + l15) * 32 + quad * 8];
#pragma unroll
        for (int j = 0; j < 2; j++)
            bf[j] = *(const bf16x8*)&sB[(wave * 32 + j * 16 + l15) * 32 + quad * 8];
#pragma unroll
        for (int i = 0; i < 4; i++)
#pragma unroll
            for (int j = 0; j < 2; j++)
                acc[i][j] = __builtin_amdgcn_mfma_f32_16x16x32_bf16(af[i], bf[j], acc[i][j], 0, 0, 0);

        __builtin_amdgcn_s_barrier();
    }
#undef OSTAGE

    float bv[2];
#pragma unroll
    for (int j = 0; j < 2; j++)
        bv[j] = (float)bias[bn + wave * 32 + j * 16 + l15];
#pragma unroll
    for (int i = 0; i < 4; i++) {
#pragma unroll
        for (int j = 0; j < 2; j++) {
            int col = bn + wave * 32 + j * 16 + l15;
#pragma unroll
            for (int r = 0; r < 4; r++) {
                int row = bm + i * 16 + quad * 4 + r;
                float v = acc[i][j][r] + bv[j];
                if (OF32) ((float*)C)[(size_t)row * N + col] = v;
                else      ((__hip_bfloat16*)C)[(size_t)row * N + col] = (__hip_bfloat16)v;
            }
        }
    }
}

__global__ __launch_bounds__(256, 2) void out_gemm(
    const __hip_bfloat16* __restrict__ A, const __hip_bfloat16* __restrict__ W,
    const __hip_bfloat16* __restrict__ bias, const void* __restrict__ origW,
    void* __restrict__ C, int M, int N, int K)
{
    __shared__ __hip_bfloat16 smem[2 * 6144];
    __shared__ int f32flag;
    if (threadIdx.x == 0) f32flag = sniff_f32(origW);
    __syncthreads();
    if (f32flag)
        gemm64_body<true>(A, W, bias, C, M, N, K, blockIdx.x * 64, blockIdx.y * 128, smem);
    else
        gemm64_body<false>(A, W, bias, C, M, N, K, blockIdx.x * 64, blockIdx.y * 128, smem);
}

// ---------------------------------------------------------------------------
// Flash attention, causal, no-max softmax, S^T formulation.
// R18: 256-row q-tile, 8 waves x 32 q-rows (R0's g-loop body). K/V frags are
// wave-replicated LDS reads, so bigger rows/wave halves frag traffic per row.
// Double-buffered K/VT, ONE barrier per iter. grid (8,16,2); qt = bz?7-bx:bx.
// (512,4): VGPR cap 128 >= ~100 working set. Do NOT raise waves/EU (R16).
// ---------------------------------------------------------------------------
#define PAD 68

__global__ __launch_bounds__(512, 4) void attn_causal(
    const __hip_bfloat16* __restrict__ Q,
    const __hip_bfloat16* __restrict__ K,
    const __hip_bfloat16* __restrict__ VT,
    __hip_bfloat16* __restrict__ O,
    int T, int D, int H)
{
    __shared__ __hip_bfloat16 sK[2][64 * PAD];
    __shared__ __hip_bfloat16 sVT[2][64 * PAD];
    __shared__ __hip_bfloat16 sPA[8][32 * PAD];   // per-wave P (32 q-rows)

    const int tid  = threadIdx.x;
    const int wave = tid >> 6;      // 0..7
    const int lane = tid & 63;
    const int quad = lane >> 4;
    const int l15  = lane & 15;

    const int NT = T >> 8;  // 8 q-tiles of 256
    const int qt = blockIdx.z ? (NT - 1 - (int)blockIdx.x) : (int)blockIdx.x;
    const int h  = blockIdx.y;
    const int b  = blockIdx.z;
    const size_t headoff = (size_t)b * T * D + (size_t)h * 64;
    const size_t vtoff   = ((size_t)b * H + h) * 64 * (size_t)T;

    const int nkt = 4 * qt + 4;
    const int qbase    = qt * 256 + wave * 32;
    const int myrowmax = qbase + 31;

    // Q B-operand fragments in registers (block-lifetime constant)
    bf16x8 qfrag[2][2];
#pragma unroll
    for (int g = 0; g < 2; g++)
#pragma unroll
        for (int kk = 0; kk < 2; kk++)
            qfrag[g][kk] = *(const bf16x8*)&Q[headoff +
                (size_t)(qbase + g * 16 + l15) * D + kk * 32 + quad * 8];

    f32x4 acc_o[2][4];
#pragma unroll
    for (int g = 0; g < 2; g++)
#pragma unroll
        for (int j = 0; j < 4; j++) acc_o[g][j] = (f32x4)0.0f;
    float lacc[2] = {0.f, 0.f};   // per-lane l for q = qbase + g*16 + l15

    const int srow = tid >> 3;        // 0..63: one 16B chunk per thread
    const int sc8  = (tid & 7) * 8;

    // pre-loop: stage kt=0 into buf0, prefetch kt=1
    bf16x8 pk, pv;
    pk = *(const bf16x8*)&K[headoff + (size_t)srow * D + sc8];
    pv = *(const bf16x8*)&VT[vtoff + (size_t)srow * T + sc8];
    *(bf16x8*)&sK[0][srow * PAD + sc8]  = pk;
    *(bf16x8*)&sVT[0][srow * PAD + sc8] = pv;
    if (nkt > 1) {
        pk = *(const bf16x8*)&K[headoff + (size_t)(64 + srow) * D + sc8];
        pv = *(const bf16x8*)&VT[vtoff + (size_t)srow * T + 64 + sc8];
    }
    __syncthreads();

    for (int kt = 0; kt < nkt; ++kt) {
        const int cur = kt & 1;

        // stage next tile into the other buffer (safe: barrier at end of kt-1)
        if (kt + 1 < nkt) {
            *(bf16x8*)&sK[1 - cur][srow * PAD + sc8]  = pk;
            *(bf16x8*)&sVT[1 - cur][srow * PAD + sc8] = pv;
            if (kt + 2 < nkt) {
                pk = *(const bf16x8*)&K[headoff + (size_t)((kt + 2) * 64 + srow) * D + sc8];
                pv = *(const bf16x8*)&VT[vtoff + (size_t)srow * T + (kt + 2) * 64 + sc8];
            }
        }

        if (kt * 64 <= myrowmax) {
            // K/V fragments once per iter, reused for both q-groups
            bf16x8 kfrag[2][4], vfrag[2][4];
#pragma unroll
            for (int kk = 0; kk < 2; kk++)
#pragma unroll
                for (int j = 0; j < 4; j++) {
                    kfrag[kk][j] = *(const bf16x8*)&sK[cur][(j * 16 + l15) * PAD + kk * 32 + quad * 8];
                    vfrag[kk][j] = *(const bf16x8*)&sVT[cur][(j * 16 + l15) * PAD + kk * 32 + quad * 8];
                }

#pragma unroll
            for (int g = 0; g < 2; g++) {
                const int qb = qbase + g * 16;
                f32x4 st[4];
#pragma unroll
                for (int j = 0; j < 4; j++) st[j] = (f32x4)0.0f;
                __builtin_amdgcn_s_setprio(1);
#pragma unroll
                for (int kk = 0; kk < 2; kk++)
#pragma unroll
                    for (int j = 0; j < 4; j++)
                        st[j] = __builtin_amdgcn_mfma_f32_16x16x32_bf16(
                            kfrag[kk][j], qfrag[g][kk], st[j], 0, 0, 0);
                __builtin_amdgcn_s_setprio(0);

                if (kt * 64 + 63 > qb) {   // wave-uniform mask check (diag)
                    const int q = qb + l15;
#pragma unroll
                    for (int j = 0; j < 4; j++) {
                        int keyb = kt * 64 + j * 16 + quad * 4;
#pragma unroll
                        for (int r = 0; r < 4; r++)
                            if (keyb + r > q) st[j][r] = -1e30f;
                    }
                }

#pragma unroll
                for (int j = 0; j < 4; j++) {
                    union { __hip_bfloat16 e[4]; s16x4 v; } u;
#pragma unroll
                    for (int r = 0; r < 4; r++) {
                        float p = exp2f(st[j][r]);
                        lacc[g] += p;
                        u.e[r] = (__hip_bfloat16)p;
                    }
                    // 4 contiguous keys at row q: one b64 write
                    *(s16x4*)&sPA[wave][(g * 16 + l15) * PAD + j * 16 + quad * 4] = u.v;
                }
            }
            // sPA wave-local: lgkmcnt orders write->read, no barrier.
            __builtin_amdgcn_s_setprio(1);
#pragma unroll
            for (int g = 0; g < 2; g++)
#pragma unroll
                for (int kk = 0; kk < 2; kk++) {
                    bf16x8 a = *(const bf16x8*)&sPA[wave][(g * 16 + l15) * PAD + kk * 32 + quad * 8];
#pragma unroll
                    for (int j = 0; j < 4; j++)
                        acc_o[g][j] = __builtin_amdgcn_mfma_f32_16x16x32_bf16(
                            a, vfrag[kk][j], acc_o[g][j], 0, 0, 0);
                }
            __builtin_amdgcn_s_setprio(0);
        }

        __syncthreads();   // single barrier per iter
    }

    // l lives per-lane (partial over quads): reduce across quads
#pragma unroll
    for (int g = 0; g < 2; g++) {
        lacc[g] += __shfl_xor(lacc[g], 16, 64);
        lacc[g] += __shfl_xor(lacc[g], 32, 64);
    }

    // acc_o rows are q = quad*4+r: fetch l from lane quad*4+r via shfl
#pragma unroll
    for (int g = 0; g < 2; g++)
#pragma unroll
        for (int r = 0; r < 4; r++) {
            float linv = 1.0f / __shfl(lacc[g], quad * 4 + r, 64);
            int row = qbase + g * 16 + quad * 4 + r;
#pragma unroll
            for (int j = 0; j < 4; j++) {
                int col = j * 16 + l15;
                O[headoff + (size_t)row * D + col] = (__hip_bfloat16)(acc_o[g][j][r] * linv);
            }
        }
}

// ---------------------------------------------------------------------------
extern "C" void kernel_launch(void* const* d_in, const int* in_sizes, int n_in,
                              void* d_out, int out_size, void* d_ws, size_t ws_size,
                              hipStream_t stream) {
    const int Bb = 2, T = 2048, D = 1024, H = 16;
    const int M = Bb * T;   // 4096

    __hip_bfloat16* w = (__hip_bfloat16*)d_ws;
    __hip_bfloat16* Q   = w;
    __hip_bfloat16* Kb  = Q   + (size_t)M * D;
    __hip_bfloat16* VT  = Kb  + (size_t)M * D;
    __hip_bfloat16* ctx = VT  + (size_t)M * D;
    __hip_bfloat16* xb  = ctx + (size_t)M * D;
    __hip_bfloat16* Wqb = xb  + (size_t)M * D;
    __hip_bfloat16* Wkb = Wqb + (size_t)D * D;
    __hip_bfloat16* Wvb = Wkb + (size_t)D * D;
    __hip_bfloat16* Wob = Wvb + (size_t)D * D;
    __hip_bfloat16* bqb = Wob + (size_t)D * D;
    __hip_bfloat16* bkb = bqb + D;
    __hip_bfloat16* bvb = bkb + D;
    __hip_bfloat16* bob = bvb + D;

    CvtPack pk;
    pk.a[0] = { d_in[0], xb,  M * D };
    pk.a[1] = { d_in[1], Wqb, D * D };
    pk.a[2] = { d_in[2], bqb, D };
    pk.a[3] = { d_in[3], Wkb, D * D };
    pk.a[4] = { d_in[4], bkb, D };
    pk.a[5] = { d_in[5], Wvb, D * D };
    pk.a[6] = { d_in[6], bvb, D };
    pk.a[7] = { d_in[7], Wob, D * D };
    pk.a[8] = { d_in[8], bob, D };

    cvt_bf16<<<dim3(512, 9), 256, 0, stream>>>(pk);
    qkv_gemm<<<dim3(M / 128, D / 128, 3), 256, 0, stream>>>(
        xb, Wqb, bqb, Q, Wkb, bkb, Kb, Wvb, bvb, VT, M, D, D);
    attn_causal<<<dim3(T / 256, H, Bb), 512, 0, stream>>>(Q, Kb, VT, ctx, T, D, H);
    out_gemm<<<dim3(M / 64, D / 128), 256, 0, stream>>>(
        ctx, Wob, bob, d_in[7], d_out, M, D, D);
}

// Round 11
// 209.852 us; speedup vs baseline: 1.7898x; 1.7898x over previous
//
#include <hip/hip_runtime.h>
#include <hip/hip_bf16.h>

// MHA forward: B=2, T=2048, D=1024, H=16 (head dim 64), causal. fp32 I/O (sniffed).
// R19: exact R13 revert (best: 206.8us) + ONE change: qkv/out launch_bounds
//      (256,2)->(256,3). Rationale: non-attn budget is ~159us and qkv (~26GF)
//      is the bulk => ~400TF, likely VGPR-residency-limited (cap 256 at (,2)
//      -> allocator free to use ~160-200 VGPR -> 2 blocks/CU despite 34.8KB
//      LDS fitting 4). (,3) caps at 170 (40-reg margin over ~130 working set,
//      UNLIKE R16/R18's below-need caps) -> 3 blocks/CU, 768-block grid fully
//      resident.
//      Allocator lessons (do not retry): 512-thread attn is pinned at 64 VGPR
//      regardless of bounds; >64 working sets spill (R10/R16/R18). R9 attn
//      body @ (512,4) is the attn local optimum (46.5us).

typedef __attribute__((ext_vector_type(8))) short bf16x8;   // MFMA A/B frag
typedef __attribute__((ext_vector_type(4))) float f32x4;    // MFMA C/D frag
typedef __attribute__((ext_vector_type(4))) short s16x4;    // 4 bf16 = b64

#define QSCALE 0.18033688011f   // (1/sqrt(64)) * log2(e)

__device__ __forceinline__ int sniff_f32(const void* p) {
    const unsigned short* u = (const unsigned short*)p;
    int c = 0;
    for (int i = 0; i < 256; ++i) {
        int e = (u[i] >> 7) & 0xFF;
        c += (e >= 0x90) ? 1 : 0;
    }
    return c > 8;
}

__device__ __forceinline__ void async_copy16(const void* g, void* l) {
    __builtin_amdgcn_global_load_lds(
        (const __attribute__((address_space(1))) void*)g,
        (__attribute__((address_space(3))) void*)l, 16, 0, 0);
}

// ---------------------------------------------------------------------------
// Convert pass (unchanged)
// ---------------------------------------------------------------------------
struct Cvt { const void* src; __hip_bfloat16* dst; int n; };
struct CvtPack { Cvt a[9]; };

__global__ __launch_bounds__(256) void cvt_bf16(CvtPack pk) {
    const Cvt c = pk.a[blockIdx.y];
    const int f32 = sniff_f32(c.src);
    const int stride = gridDim.x * 256 * 8;
    for (int idx = (blockIdx.x * 256 + threadIdx.x) * 8; idx < c.n; idx += stride) {
        if (f32) {
            const float* s = (const float*)c.src + idx;
            f32x4 a0 = *(const f32x4*)s;
            f32x4 a1 = *(const f32x4*)(s + 4);
            union { __hip_bfloat16 h[8]; bf16x8 v; } u;
#pragma unroll
            for (int e = 0; e < 4; e++) u.h[e]     = (__hip_bfloat16)a0[e];
#pragma unroll
            for (int e = 0; e < 4; e++) u.h[4 + e] = (__hip_bfloat16)a1[e];
            *(bf16x8*)&c.dst[idx] = u.v;
        } else {
            *(bf16x8*)&c.dst[idx] = *(const bf16x8*)((const __hip_bfloat16*)c.src + idx);
        }
    }
}

// ---------------------------------------------------------------------------
// 128x128 GEMM-BT, 2-phase prefetch (R13). MODE: 0 = bf16 row-major out,
// 1 = fp32 row-major out, 2 = bf16 out into VT[b][h][d][t] via LDS-staged
// coalesced writes.
// ---------------------------------------------------------------------------
template <int MODE>
__device__ __forceinline__ void gemm_async_body(
    const __hip_bfloat16* __restrict__ A, const __hip_bfloat16* __restrict__ W,
    const __hip_bfloat16* __restrict__ bias, void* __restrict__ C,
    int M, int N, int K, int bm, int bn, float outscale,
    __hip_bfloat16* smem)
{
    const int tid  = threadIdx.x;
    const int wave = tid >> 6;
    const int lane = tid & 63;
    const int quad = lane >> 4;
    const int l15  = lane & 15;
    const int wr   = wave >> 1;
    const int wc   = wave & 1;

    const int srow = wave * 16 + (lane >> 2);
    const int scol = (lane & 3) * 8;
    const __hip_bfloat16* gA0 = A + (size_t)(bm + srow) * K + scol;
    const __hip_bfloat16* gB0 = W + (size_t)(bn + srow) * K + scol;

    f32x4 acc[4][4];
#pragma unroll
    for (int i = 0; i < 4; i++)
#pragma unroll
        for (int j = 0; j < 4; j++) acc[i][j] = (f32x4)0.0f;

#define QSTAGE(buf, k0) { \
        __hip_bfloat16* d_ = smem + (buf) * 8192 + wave * 512; \
        async_copy16(gA0 + (k0), d_); \
        async_copy16(gA0 + (size_t)64 * K + (k0), d_ + 2048); \
        async_copy16(gB0 + (k0), d_ + 4096); \
        async_copy16(gB0 + (size_t)64 * K + (k0), d_ + 4096 + 2048); \
    }

    const int nt = K >> 5;
    QSTAGE(0, 0);
    for (int t = 0; t < nt; ++t) {
        const int buf = t & 1;
        const __hip_bfloat16* sA = smem + buf * 8192;
        const __hip_bfloat16* sB = sA + 4096;
        if (t + 1 < nt) {
            QSTAGE(1 - buf, (t + 1) * 32);
            asm volatile("s_waitcnt vmcnt(4)" ::: "memory");
        } else {
            asm volatile("s_waitcnt vmcnt(0)" ::: "memory");
        }
        __builtin_amdgcn_s_barrier();

        bf16x8 af[4], bf[4];
#pragma unroll
        for (int i = 0; i < 4; i++)
            af[i] = *(const bf16x8*)&sA[(wr * 64 + i * 16 + l15) * 32 + quad * 8];
#pragma unroll
        for (int j = 0; j < 4; j++)
            bf[j] = *(const bf16x8*)&sB[(wc * 64 + j * 16 + l15) * 32 + quad * 8];
#pragma unroll
        for (int i = 0; i < 4; i++)
#pragma unroll
            for (int j = 0; j < 4; j++)
                acc[i][j] = __builtin_amdgcn_mfma_f32_16x16x32_bf16(af[i], bf[j], acc[i][j], 0, 0, 0);

        __builtin_amdgcn_s_barrier();
    }
#undef QSTAGE

    float bv[4];
#pragma unroll
    for (int j = 0; j < 4; j++)
        bv[j] = (float)bias[bn + wc * 64 + j * 16 + l15];

    if (MODE == 2) {
        __hip_bfloat16* sOut = smem;
        __syncthreads();
#pragma unroll
        for (int i = 0; i < 4; i++) {
            int tl = wr * 64 + i * 16 + quad * 4;
#pragma unroll
            for (int j = 0; j < 4; j++) {
                int dl = wc * 64 + j * 16 + l15;
                union { __hip_bfloat16 e[4]; s16x4 v; } u;
#pragma unroll
                for (int r = 0; r < 4; r++)
                    u.e[r] = (__hip_bfloat16)(acc[i][j][r] + bv[j]);
                *(s16x4*)&sOut[dl * 136 + tl] = u.v;
            }
        }
        __syncthreads();
        __hip_bfloat16* VTo = (__hip_bfloat16*)C;
        const int bb = bm >> 11, tt0 = bm & 2047;
#pragma unroll
        for (int g8 = 0; g8 < 8; g8++) {
            int idx = g8 * 256 + tid;
            int dl  = idx >> 4;
            int tc  = (idx & 15) * 8;
            int dg  = bn + dl;
            bf16x8 v = *(const bf16x8*)&sOut[dl * 136 + tc];
            *(bf16x8*)&VTo[(((size_t)bb * 16 + (dg >> 6)) * 64 + (dg & 63)) * 2048 + tt0 + tc] = v;
        }
    } else {
#pragma unroll
        for (int i = 0; i < 4; i++) {
#pragma unroll
            for (int j = 0; j < 4; j++) {
                int col = bn + wc * 64 + j * 16 + l15;
#pragma unroll
                for (int r = 0; r < 4; r++) {
                    int row = bm + wr * 64 + i * 16 + quad * 4 + r;
                    float v = (acc[i][j][r] + bv[j]) * outscale;
                    if (MODE == 1) ((float*)C)[(size_t)row * N + col] = v;
                    else ((__hip_bfloat16*)C)[(size_t)row * N + col] = (__hip_bfloat16)v;
                }
            }
        }
    }
}

__global__ __launch_bounds__(256, 3) void qkv_gemm(
    const __hip_bfloat16* __restrict__ x,
    const __hip_bfloat16* __restrict__ Wq, const __hip_bfloat16* __restrict__ bq, __hip_bfloat16* __restrict__ Q,
    const __hip_bfloat16* __restrict__ Wk, const __hip_bfloat16* __restrict__ bk, __hip_bfloat16* __restrict__ Kb,
    const __hip_bfloat16* __restrict__ Wv, const __hip_bfloat16* __restrict__ bv, __hip_bfloat16* __restrict__ VT,
    int M, int N, int K)
{
    __shared__ __hip_bfloat16 smem[128 * 136];
    if (blockIdx.z == 0)
        gemm_async_body<0>(x, Wq, bq, Q, M, N, K, blockIdx.x * 128, blockIdx.y * 128, QSCALE, smem);
    else if (blockIdx.z == 1)
        gemm_async_body<0>(x, Wk, bk, Kb, M, N, K, blockIdx.x * 128, blockIdx.y * 128, 1.0f, smem);
    else
        gemm_async_body<2>(x, Wv, bv, VT, M, N, K, blockIdx.x * 128, blockIdx.y * 128, 1.0f, smem);
}

// ---------------------------------------------------------------------------
// out_gemm 64x128, 2-phase prefetch (R13 body)
// ---------------------------------------------------------------------------
template <bool OF32>
__device__ __forceinline__ void gemm64_body(
    const __hip_bfloat16* __restrict__ A, const __hip_bfloat16* __restrict__ W,
    const __hip_bfloat16* __restrict__ bias, void* __restrict__ C,
    int M, int N, int K, int bm, int bn,
    __hip_bfloat16* smem)
{
    const int tid  = threadIdx.x;
    const int wave = tid >> 6;
    const int lane = tid & 63;
    const int quad = lane >> 4;
    const int l15  = lane & 15;

    const int srow = wave * 16 + (lane >> 2);
    const int scol = (lane & 3) * 8;
    const __hip_bfloat16* gA0 = A + (size_t)(bm + srow) * K + scol;
    const __hip_bfloat16* gB0 = W + (size_t)(bn + srow) * K + scol;

    f32x4 acc[4][2];
#pragma unroll
    for (int i = 0; i < 4; i++)
#pragma unroll
        for (int j = 0; j < 2; j++) acc[i][j] = (f32x4)0.0f;

#define OSTAGE(buf, k0) { \
        __hip_bfloat16* d_ = smem + (buf) * 6144; \
        async_copy16(gA0 + (k0), d_ + wave * 512); \
        async_copy16(gB0 + (k0), d_ + 2048 + wave * 512); \
        async_copy16(gB0 + (size_t)64 * K + (k0), d_ + 2048 + wave * 512 + 2048); \
    }

    const int nt = K >> 5;
    OSTAGE(0, 0);
    for (int t = 0; t < nt; ++t) {
        const int buf = t & 1;
        const __hip_bfloat16* sA = smem + buf * 6144;
        const __hip_bfloat16* sB = sA + 2048;
        if (t + 1 < nt) {
            OSTAGE(1 - buf, (t + 1) * 32);
            asm volatile("s_waitcnt vmcnt(3)" ::: "memory");
        } else {
            asm volatile("s_waitcnt vmcnt(0)" ::: "memory");
        }
        __builtin_amdgcn_s_barrier();

        bf16x8 af[4], bf[2];
#pragma unroll
        for (int i = 0; i < 4; i++)
            af[i] = *(const bf16x8*)&sA[(i * 16 + l15) * 32 + quad * 8];
#pragma unroll
        for (int j = 0; j < 2; j++)
            bf[j] = *(const bf16x8*)&sB[(wave * 32 + j * 16 + l15) * 32 + quad * 8];
#pragma unroll
        for (int i = 0; i < 4; i++)
#pragma unroll
            for (int j = 0; j < 2; j++)
                acc[i][j] = __builtin_amdgcn_mfma_f32_16x16x32_bf16(af[i], bf[j], acc[i][j], 0, 0, 0);

        __builtin_amdgcn_s_barrier();
    }
#undef OSTAGE

    float bv[2];
#pragma unroll
    for (int j = 0; j < 2; j++)
        bv[j] = (float)bias[bn + wave * 32 + j * 16 + l15];
#pragma unroll
    for (int i = 0; i < 4; i++) {
#pragma unroll
        for (int j = 0; j < 2; j++) {
            int col = bn + wave * 32 + j * 16 + l15;
#pragma unroll
            for (int r = 0; r < 4; r++) {
                int row = bm + i * 16 + quad * 4 + r;
                float v = acc[i][j][r] + bv[j];
                if (OF32) ((float*)C)[(size_t)row * N + col] = v;
                else      ((__hip_bfloat16*)C)[(size_t)row * N + col] = (__hip_bfloat16)v;
            }
        }
    }
}

__global__ __launch_bounds__(256, 3) void out_gemm(
    const __hip_bfloat16* __restrict__ A, const __hip_bfloat16* __restrict__ W,
    const __hip_bfloat16* __restrict__ bias, const void* __restrict__ origW,
    void* __restrict__ C, int M, int N, int K)
{
    __shared__ __hip_bfloat16 smem[2 * 6144];
    __shared__ int f32flag;
    if (threadIdx.x == 0) f32flag = sniff_f32(origW);
    __syncthreads();
    if (f32flag)
        gemm64_body<true>(A, W, bias, C, M, N, K, blockIdx.x * 64, blockIdx.y * 128, smem);
    else
        gemm64_body<false>(A, W, bias, C, M, N, K, blockIdx.x * 64, blockIdx.y * 128, smem);
}

// ---------------------------------------------------------------------------
// Flash attention, causal, no-max softmax, S^T formulation.  (R9/R13 verbatim)
// 128-row q-tile, EIGHT waves x 16 q-rows. Double-buffered K/VT tiles,
// ONE barrier per iter. grid (16,16,2); qt = bz ? 15-bx : bx.
// (512,4): VGPR 64, 2 blocks/CU. Allocator pins 512-thread kernels at 64 VGPR;
// bigger working sets spill (R10/R16/R18) — do not restructure.
// ---------------------------------------------------------------------------
#define PAD 68

__global__ __launch_bounds__(512, 4) void attn_causal(
    const __hip_bfloat16* __restrict__ Q,
    const __hip_bfloat16* __restrict__ K,
    const __hip_bfloat16* __restrict__ VT,
    __hip_bfloat16* __restrict__ O,
    int T, int D, int H)
{
    __shared__ __hip_bfloat16 sK[2][64 * PAD];
    __shared__ __hip_bfloat16 sVT[2][64 * PAD];
    __shared__ __hip_bfloat16 sPA[8][16 * PAD];   // per-wave P in A-layout

    const int tid  = threadIdx.x;
    const int wave = tid >> 6;      // 0..7
    const int lane = tid & 63;
    const int quad = lane >> 4;
    const int l15  = lane & 15;

    const int NT = T >> 7;  // 16 q-tiles of 128
    const int qt = blockIdx.z ? (NT - 1 - (int)blockIdx.x) : (int)blockIdx.x;
    const int h  = blockIdx.y;
    const int b  = blockIdx.z;
    const size_t headoff = (size_t)b * T * D + (size_t)h * 64;
    const size_t vtoff   = ((size_t)b * H + h) * 64 * (size_t)T;

    const int nkt = 2 * qt + 2;
    const int qbase    = qt * 128 + wave * 16;
    const int myrowmax = qbase + 15;

    // Q B-operand fragments in registers (block-lifetime constant)
    bf16x8 qfrag[2];
#pragma unroll
    for (int kk = 0; kk < 2; kk++)
        qfrag[kk] = *(const bf16x8*)&Q[headoff +
            (size_t)(qbase + l15) * D + kk * 32 + quad * 8];

    f32x4 acc_o[4];
#pragma unroll
    for (int j = 0; j < 4; j++) acc_o[j] = (f32x4)0.0f;
    float lacc = 0.f;   // per-lane l for q = qbase + l15 (partial over quads)

    const int srow = tid >> 3;        // 0..63: one 16B chunk per thread
    const int sc8  = (tid & 7) * 8;

    // pre-loop: stage kt=0 into buf0, prefetch kt=1
    bf16x8 pk, pv;
    pk = *(const bf16x8*)&K[headoff + (size_t)srow * D + sc8];
    pv = *(const bf16x8*)&VT[vtoff + (size_t)srow * T + sc8];
    *(bf16x8*)&sK[0][srow * PAD + sc8]  = pk;
    *(bf16x8*)&sVT[0][srow * PAD + sc8] = pv;
    if (nkt > 1) {
        pk = *(const bf16x8*)&K[headoff + (size_t)(64 + srow) * D + sc8];
        pv = *(const bf16x8*)&VT[vtoff + (size_t)srow * T + 64 + sc8];
    }
    __syncthreads();

    for (int kt = 0; kt < nkt; ++kt) {
        const int cur = kt & 1;

        // stage next tile into the other buffer (safe: barrier at end of kt-1
        // means all waves finished reading it in kt-1)
        if (kt + 1 < nkt) {
            *(bf16x8*)&sK[1 - cur][srow * PAD + sc8]  = pk;
            *(bf16x8*)&sVT[1 - cur][srow * PAD + sc8] = pv;
            if (kt + 2 < nkt) {
                pk = *(const bf16x8*)&K[headoff + (size_t)((kt + 2) * 64 + srow) * D + sc8];
                pv = *(const bf16x8*)&VT[vtoff + (size_t)srow * T + (kt + 2) * 64 + sc8];
            }
        }

        if (kt * 64 <= myrowmax) {
            // K/V fragments (A-operand = rows of K / rows of VT)
            bf16x8 kfrag[2][4], vfrag[2][4];
#pragma unroll
            for (int kk = 0; kk < 2; kk++)
#pragma unroll
                for (int j = 0; j < 4; j++) {
                    kfrag[kk][j] = *(const bf16x8*)&sK[cur][(j * 16 + l15) * PAD + kk * 32 + quad * 8];
                    vfrag[kk][j] = *(const bf16x8*)&sVT[cur][(j * 16 + l15) * PAD + kk * 32 + quad * 8];
                }

            f32x4 st[4];
#pragma unroll
            for (int j = 0; j < 4; j++) st[j] = (f32x4)0.0f;
            __builtin_amdgcn_s_setprio(1);
#pragma unroll
            for (int kk = 0; kk < 2; kk++)
#pragma unroll
                for (int j = 0; j < 4; j++)
                    st[j] = __builtin_amdgcn_mfma_f32_16x16x32_bf16(
                        kfrag[kk][j], qfrag[kk], st[j], 0, 0, 0);
            __builtin_amdgcn_s_setprio(0);

            if (kt * 64 + 63 > qbase) {   // wave-uniform mask check (diag tile)
                const int q = qbase + l15;
#pragma unroll
                for (int j = 0; j < 4; j++) {
                    int keyb = kt * 64 + j * 16 + quad * 4;
#pragma unroll
                    for (int r = 0; r < 4; r++)
                        if (keyb + r > q) st[j][r] = -1e30f;
                }
            }

#pragma unroll
            for (int j = 0; j < 4; j++) {
                union { __hip_bfloat16 e[4]; s16x4 v; } u;
#pragma unroll
                for (int r = 0; r < 4; r++) {
                    float p = exp2f(st[j][r]);
                    lacc += p;
                    u.e[r] = (__hip_bfloat16)p;
                }
                // 4 contiguous keys at row q=l15: one b64 write
                *(s16x4*)&sPA[wave][l15 * PAD + j * 16 + quad * 4] = u.v;
            }
            // sPA wave-local: lgkmcnt orders write->read, no barrier.
            __builtin_amdgcn_s_setprio(1);
#pragma unroll
            for (int kk = 0; kk < 2; kk++) {
                bf16x8 a = *(const bf16x8*)&sPA[wave][l15 * PAD + kk * 32 + quad * 8];
#pragma unroll
                for (int j = 0; j < 4; j++)
                    acc_o[j] = __builtin_amdgcn_mfma_f32_16x16x32_bf16(
                        a, vfrag[kk][j], acc_o[j], 0, 0, 0);
            }
            __builtin_amdgcn_s_setprio(0);
        }

        __syncthreads();   // single barrier per iter
    }

    // l lives per-lane for q=l15 (partial over quads): reduce across quads
    lacc += __shfl_xor(lacc, 16, 64);
    lacc += __shfl_xor(lacc, 32, 64);

    // acc_o rows are q = quad*4+r: fetch l from lane quad*4+r via shfl
#pragma unroll
    for (int r = 0; r < 4; r++) {
        float linv = 1.0f / __shfl(lacc, quad * 4 + r, 64);
        int row = qbase + quad * 4 + r;
#pragma unroll
        for (int j = 0; j < 4; j++) {
            int col = j * 16 + l15;
            O[headoff + (size_t)row * D + col] = (__hip_bfloat16)(acc_o[j][r] * linv);
        }
    }
}

// ---------------------------------------------------------------------------
extern "C" void kernel_launch(void* const* d_in, const int* in_sizes, int n_in,
                              void* d_out, int out_size, void* d_ws, size_t ws_size,
                              hipStream_t stream) {
    const int Bb = 2, T = 2048, D = 1024, H = 16;
    const int M = Bb * T;   // 4096

    __hip_bfloat16* w = (__hip_bfloat16*)d_ws;
    __hip_bfloat16* Q   = w;
    __hip_bfloat16* Kb  = Q   + (size_t)M * D;
    __hip_bfloat16* VT  = Kb  + (size_t)M * D;
    __hip_bfloat16* ctx = VT  + (size_t)M * D;
    __hip_bfloat16* xb  = ctx + (size_t)M * D;
    __hip_bfloat16* Wqb = xb  + (size_t)M * D;
    __hip_bfloat16* Wkb = Wqb + (size_t)D * D;
    __hip_bfloat16* Wvb = Wkb + (size_t)D * D;
    __hip_bfloat16* Wob = Wvb + (size_t)D * D;
    __hip_bfloat16* bqb = Wob + (size_t)D * D;
    __hip_bfloat16* bkb = bqb + D;
    __hip_bfloat16* bvb = bkb + D;
    __hip_bfloat16* bob = bvb + D;

    CvtPack pk;
    pk.a[0] = { d_in[0], xb,  M * D };
    pk.a[1] = { d_in[1], Wqb, D * D };
    pk.a[2] = { d_in[2], bqb, D };
    pk.a[3] = { d_in[3], Wkb, D * D };
    pk.a[4] = { d_in[4], bkb, D };
    pk.a[5] = { d_in[5], Wvb, D * D };
    pk.a[6] = { d_in[6], bvb, D };
    pk.a[7] = { d_in[7], Wob, D * D };
    pk.a[8] = { d_in[8], bob, D };

    cvt_bf16<<<dim3(512, 9), 256, 0, stream>>>(pk);
    qkv_gemm<<<dim3(M / 128, D / 128, 3), 256, 0, stream>>>(
        xb, Wqb, bqb, Q, Wkb, bkb, Kb, Wvb, bvb, VT, M, D, D);
    attn_causal<<<dim3(T / 128, H, Bb), 512, 0, stream>>>(Q, Kb, VT, ctx, T, D, H);
    out_gemm<<<dim3(M / 64, D / 128), 256, 0, stream>>>(
        ctx, Wob, bob, d_in[7], d_out, M, D, D);
}